// Round 9
// baseline (310.792 us; speedup 1.0000x reference)
//
#include <hip/hip_runtime.h>
#include <hip/hip_bf16.h>

#define NN 4096
#define KK 64
#define AA 8
#define DD 128

#define XH_STRIDE 264   // shorts: 256 + 8 pad (rows 16B-aligned)
#define A_STRIDE  136
#define H2_STRIDE 136
#define XREG_SZ   16896 // 64 * 264 shorts = 33792 B

typedef __bf16 bf16x8 __attribute__((ext_vector_type(8)));
typedef __bf16 bf16x2 __attribute__((ext_vector_type(2)));
typedef float  f32x4  __attribute__((ext_vector_type(4)));

__device__ __forceinline__ short f2bf(float f) {
    unsigned u = __builtin_bit_cast(unsigned, f);
    u += 0x7FFFu + ((u >> 16) & 1u);   // RNE
    return (short)(u >> 16);
}
__device__ __forceinline__ float bf2f(short s) {
    unsigned u = ((unsigned)(unsigned short)s) << 16;
    return __builtin_bit_cast(float, u);
}
__device__ __forceinline__ unsigned f2bf2(float a, float b) {
#if __has_builtin(__builtin_amdgcn_cvt_pk_bf16_f32)
    bf16x2 r = __builtin_amdgcn_cvt_pk_bf16_f32(a, b);
    return __builtin_bit_cast(unsigned, r);
#else
    return ((unsigned)(unsigned short)f2bf(a)) | (((unsigned)(unsigned short)f2bf(b)) << 16);
#endif
}
__device__ __forceinline__ void store_bf8(short* dst, float4 a, float4 b) {
    uint4 v;
    v.x = f2bf2(a.x, a.y); v.y = f2bf2(a.z, a.w);
    v.z = f2bf2(b.x, b.y); v.w = f2bf2(b.z, b.w);
    *(uint4*)dst = v;
}

// Merged prep: blocks [0,768) pack weights; blocks [768,768+512) compute s1, 8 nodes/block.
__global__ void prep_all(const float* __restrict__ W1, const float* __restrict__ W2,
                         const float* __restrict__ A1, const float* __restrict__ A2,
                         const int* __restrict__ nodes, const float* __restrict__ u2e,
                         const float* __restrict__ ab1,
                         short* __restrict__ W1p, short* __restrict__ W2p,
                         short* __restrict__ A1p, short* __restrict__ A2p,
                         float* __restrict__ s1g)
{
    if (blockIdx.x < 768) {
        int t = blockIdx.x * 256 + threadIdx.x;
        const float* src; short* dst; int Ncols, ksl, idx;
        if (t < 131072)      { src = W1; dst = W1p; Ncols = 256; ksl = 4; idx = t; }
        else if (t < 163840) { src = W2; dst = W2p; Ncols = 128; ksl = 3; idx = t - 131072; }
        else if (t < 180224) { src = A1; dst = A1p; Ncols = 128; ksl = 2; idx = t - 163840; }
        else                 { src = A2; dst = A2p; Ncols = 128; ksl = 2; idx = t - 180224; }
        int j     = idx & 7;
        int lane  = (idx >> 3) & 63;
        int fi    = idx >> 9;
        int kstep = fi & ((1 << ksl) - 1);
        int ntile = fi >> ksl;
        int k  = kstep * 32 + (lane >> 4) * 8 + j;
        int nn = ntile * 16 + (lane & 15);
        dst[idx] = f2bf(src[(size_t)k * Ncols + nn]);
    } else {
        // s1[n] = ab1 + u2e[nodes[n]] @ A1[128:256,:], 8 nodes/block
        __shared__ float rows[8][DD];
        const int b = blockIdx.x - 768;
        {
            const int r  = threadIdx.x >> 5;
            const int c4 = (threadIdx.x & 31) * 4;
            const int node = nodes[b * 8 + r];
            *(float4*)&rows[r][c4] = *(const float4*)&u2e[(size_t)node * DD + c4];
        }
        __syncthreads();
        const int h = threadIdx.x >> 7;
        const int c = threadIdx.x & 127;
        const float ab = ab1[c];
        float acc[4] = {ab, ab, ab, ab};
        for (int i = 0; i < DD; ++i) {
            const float av = A1[(size_t)(DD + i) * DD + c];
#pragma unroll
            for (int j = 0; j < 4; ++j)
                acc[j] = fmaf(rows[h * 4 + j][i], av, acc[j]);
        }
#pragma unroll
        for (int j = 0; j < 4; ++j)
            s1g[(size_t)(b * 8 + h * 4 + j) * DD + c] = acc[j];
    }
}

// launch_bounds MUST stay (512,4): (512,6) caps regs at ~85/wave -> acc spill (R6:
// +280 MB scratch traffic, 203->264 us). Budget is 128 unified regs/wave; baseline
// ~64V + ~48A. R8 showed manual 18-deep gather interleave overflows this (43 MB
// WRITE = spill). Keep any added register pressure <= ~16 regs.
__launch_bounds__(512, 4)
__global__ void l2agg_mfma(
    const int* __restrict__ paths_rel,
    const int* __restrict__ paths_nbr,
    const int* __restrict__ attrs,
    const float* __restrict__ u2e,
    const float* __restrict__ r2e,
    const float* __restrict__ ua2e,
    const float* __restrict__ b1,
    const float* __restrict__ b2,
    const float* __restrict__ ab2,
    const float* __restrict__ A3,
    const float* __restrict__ ab3,
    const short* __restrict__ W1p,
    const short* __restrict__ W2p,
    const short* __restrict__ A1p,
    const short* __restrict__ A2p,
    const float* __restrict__ s1g,
    float* __restrict__ out)
{
    // xa: xA (stride 264) -> h1 (stride 264) -> a1 (stride 136)
    // xb: xB (stride 264) -> h2 (stride 136, persists to final reduce)
    __shared__ short xa[XREG_SZ];            // 33792 B
    __shared__ short xb[XREG_SZ];            // 33792 B
    __shared__ int   idx_u[576];             // attrs(512)+nbr(64) (dead after xB) -> partials
    __shared__ float wts8[512];              // per-wave softmax weights (wave-local)
    float* partials = (float*)idx_u;         // 512 floats, born after b5

    const int n    = blockIdx.x;
    const int tid  = threadIdx.x;
    const int lane = tid & 63;
    const int wv   = tid >> 6;    // 0..7
    const int mr   = lane & 15;
    const int q    = lane >> 4;

    // ---------- async DMA prefetch: attrs + nbr indices -> LDS ----------
    {
        const int* ab = attrs + (size_t)n * KK * AA;
        __builtin_amdgcn_global_load_lds(
            (const __attribute__((address_space(1))) void*)(ab + wv * 64 + lane),
            (__attribute__((address_space(3))) void*)(idx_u + wv * 64), 4, 0, 0);
        if (wv == 0) {
            const int* nb = paths_nbr + (size_t)n * KK;
            __builtin_amdgcn_global_load_lds(
                (const __attribute__((address_space(1))) void*)(nb + lane),
                (__attribute__((address_space(3))) void*)(idx_u + 512), 4, 0, 0);
        }
    }

    // ---------- stage xA = [r1 | r2] for 64 paths ----------
#pragma unroll
    for (int pass = 0; pass < 2; ++pass) {
        const int p  = pass * 32 + (tid >> 4);
        const int t  = tid & 15;
        const int o  = t * 8;
        const int pk = n * KK + p;
        const int i0 = paths_rel[pk * 2 + 0];
        const int i1 = paths_rel[pk * 2 + 1];
        float4 r1a = *(const float4*)&r2e[(size_t)i0 * DD + o];
        float4 r1b = *(const float4*)&r2e[(size_t)i0 * DD + o + 4];
        float4 r2a = *(const float4*)&r2e[(size_t)i1 * DD + o];
        float4 r2b = *(const float4*)&r2e[(size_t)i1 * DD + o + 4];
        store_bf8(&xa[p * XH_STRIDE + o], r1a, r1b);
        store_bf8(&xa[p * XH_STRIDE + 128 + o], r2a, r2b);
    }
    __syncthreads();   // b1: xa ready, idx DMA landed

    // ---------- GEMM1 half 1 (ks 0..7 on xa), 2-deep B prefetch ----------
    const short* W1b = W1p + wv * 2 * 16 * 512 + lane * 8;  // frag(nt,ks) = W1b[nt*8192 + ks*512]
    f32x4 acc1[4][2] = {};
    bf16x8 bfc[2], bfn[2];
#pragma unroll
    for (int nt = 0; nt < 2; ++nt) bfc[nt] = *(const bf16x8*)&W1b[nt * 8192];
#pragma unroll
    for (int ks = 0; ks < 8; ++ks) {
#pragma unroll
        for (int nt = 0; nt < 2; ++nt)
            bfn[nt] = *(const bf16x8*)&W1b[nt * 8192 + (ks + 1) * 512];
        bf16x8 af[4];
#pragma unroll
        for (int mt = 0; mt < 4; ++mt)
            af[mt] = *(const bf16x8*)&xa[(mt * 16 + mr) * XH_STRIDE + ks * 32 + q * 8];
#pragma unroll
        for (int nt = 0; nt < 2; ++nt)
#pragma unroll
            for (int mt = 0; mt < 4; ++mt)
                acc1[mt][nt] = __builtin_amdgcn_mfma_f32_16x16x32_bf16(af[mt], bfc[nt], acc1[mt][nt], 0, 0, 0);
#pragma unroll
        for (int nt = 0; nt < 2; ++nt) bfc[nt] = bfn[nt];   // ks=7 carries ks=8 frags across staging
    }

    // ---------- stage xB = [ne | ae] -> xb (xa untouched; no barrier needed before this) ----------
#pragma unroll
    for (int pass = 0; pass < 2; ++pass) {
        const int p  = pass * 32 + (tid >> 4);
        const int t  = tid & 15;
        const int o  = t * 8;
        const int nb = idx_u[512 + p];
        float4 nea = *(const float4*)&u2e[(size_t)nb * DD + o];
        float4 neb = *(const float4*)&u2e[(size_t)nb * DD + o + 4];
        float4 aea = make_float4(0.f, 0.f, 0.f, 0.f);
        float4 aeb = make_float4(0.f, 0.f, 0.f, 0.f);
#pragma unroll
        for (int a = 0; a < AA; ++a) {
            const int ai = idx_u[p * AA + a];
            float4 va = *(const float4*)&ua2e[(size_t)ai * DD + o];
            float4 vb = *(const float4*)&ua2e[(size_t)ai * DD + o + 4];
            aea.x += va.x; aea.y += va.y; aea.z += va.z; aea.w += va.w;
            aeb.x += vb.x; aeb.y += vb.y; aeb.z += vb.z; aeb.w += vb.w;
        }
        store_bf8(&xb[p * XH_STRIDE + o], nea, neb);
        store_bf8(&xb[p * XH_STRIDE + 128 + o], aea, aeb);
    }
    __syncthreads();   // b2: xb ready; all xa GEMM1h1 reads done -> xa writable later

    // ---------- GEMM1 half 2 (ks 8..15 on xb) ----------
#pragma unroll
    for (int ks = 8; ks < 16; ++ks) {
        if (ks < 15) {
#pragma unroll
            for (int nt = 0; nt < 2; ++nt)
                bfn[nt] = *(const bf16x8*)&W1b[nt * 8192 + (ks + 1) * 512];
        }
        bf16x8 af[4];
#pragma unroll
        for (int mt = 0; mt < 4; ++mt)
            af[mt] = *(const bf16x8*)&xb[(mt * 16 + mr) * XH_STRIDE + (ks - 8) * 32 + q * 8];
#pragma unroll
        for (int nt = 0; nt < 2; ++nt)
#pragma unroll
            for (int mt = 0; mt < 4; ++mt)
                acc1[mt][nt] = __builtin_amdgcn_mfma_f32_16x16x32_bf16(af[mt], bfc[nt], acc1[mt][nt], 0, 0, 0);
        if (ks < 15) {
#pragma unroll
            for (int nt = 0; nt < 2; ++nt) bfc[nt] = bfn[nt];
        }
    }

    // GEMM2 assignment: mt-pair mtb = (wv>>2)*2, nt-pair nt0 = (wv&3)*2
    const int mtb = (wv >> 2) * 2;
    const int nt0 = (wv & 3) * 2;
    const short* W2b = W2p + nt0 * 8 * 512 + lane * 8;  // frag(t2,ks) = W2b[t2*4096 + ks*512]
    bf16x8 g2c[2], g2n[2];
    g2c[0] = *(const bf16x8*)&W2b[0];
    g2c[1] = *(const bf16x8*)&W2b[4096];

    // ---------- h1 = relu(acc1 + b1) -> xa (writable since b2) ----------
#pragma unroll
    for (int nt = 0; nt < 2; ++nt) {
        const int col = (wv * 2 + nt) * 16 + mr;
        const float bb = b1[col];
#pragma unroll
        for (int mt = 0; mt < 4; ++mt)
#pragma unroll
            for (int r = 0; r < 4; r += 2) {
                unsigned pk2 = f2bf2(fmaxf(acc1[mt][nt][r] + bb, 0.f),
                                     fmaxf(acc1[mt][nt][r + 1] + bb, 0.f));
                xa[(mt * 16 + q * 4 + r)     * XH_STRIDE + col] = (short)pk2;
                xa[(mt * 16 + q * 4 + r + 1) * XH_STRIDE + col] = (short)(pk2 >> 16);
            }
    }
    __syncthreads();   // b3: h1 ready; xb GEMM1h2 reads done

    // ---------- GEMM2: h2 = relu(h1 @ W2 + b2), mt=2 x nt=2, 2-deep B prefetch ----------
    f32x4 acc2[2][2] = {};
#pragma unroll
    for (int ks = 0; ks < 8; ++ks) {
        if (ks < 7) {
            g2n[0] = *(const bf16x8*)&W2b[(ks + 1) * 512];
            g2n[1] = *(const bf16x8*)&W2b[4096 + (ks + 1) * 512];
        }
        bf16x8 af[2];
#pragma unroll
        for (int j = 0; j < 2; ++j)
            af[j] = *(const bf16x8*)&xa[((mtb + j) * 16 + mr) * XH_STRIDE + ks * 32 + q * 8];
#pragma unroll
        for (int t2 = 0; t2 < 2; ++t2)
#pragma unroll
            for (int j = 0; j < 2; ++j)
                acc2[j][t2] = __builtin_amdgcn_mfma_f32_16x16x32_bf16(af[j], g2c[t2], acc2[j][t2], 0, 0, 0);
        if (ks < 7) { g2c[0] = g2n[0]; g2c[1] = g2n[1]; }
    }

    // preload ALL GEMM3 B-frags + s1 (hidden under GEMM2 epilogue + b4)
    const short* A1b = A1p + wv * 4 * 512 + lane * 8;
    bf16x8 g3f[4];
#pragma unroll
    for (int ks = 0; ks < 4; ++ks) g3f[ks] = *(const bf16x8*)&A1b[ks * 512];
    const float s1v = s1g[(size_t)n * DD + wv * 16 + mr];

    // GEMM2 epilogue -> h2 into xb (stride 136; xb dead since b3)
#pragma unroll
    for (int t2 = 0; t2 < 2; ++t2) {
        const int col = (nt0 + t2) * 16 + mr;
        const float bb = b2[col];
#pragma unroll
        for (int j = 0; j < 2; ++j)
#pragma unroll
            for (int r = 0; r < 4; r += 2) {
                unsigned pk2 = f2bf2(fmaxf(acc2[j][t2][r] + bb, 0.f),
                                     fmaxf(acc2[j][t2][r + 1] + bb, 0.f));
                xb[((mtb + j) * 16 + q * 4 + r)     * H2_STRIDE + col] = (short)pk2;
                xb[((mtb + j) * 16 + q * 4 + r + 1) * H2_STRIDE + col] = (short)(pk2 >> 16);
            }
    }
    __syncthreads();   // b4: h2 ready; xa GEMM2 reads done

    // ---------- GEMM3: a1 = relu(h2 @ A1[:128] + s1) -> xa (stride 136) ----------
    {
        f32x4 acc3[4];
#pragma unroll
        for (int mt = 0; mt < 4; ++mt) {
            acc3[mt][0] = s1v; acc3[mt][1] = s1v; acc3[mt][2] = s1v; acc3[mt][3] = s1v;
        }
#pragma unroll
        for (int ks = 0; ks < 4; ++ks) {
            bf16x8 af[4];
#pragma unroll
            for (int mt = 0; mt < 4; ++mt)
                af[mt] = *(const bf16x8*)&xb[(mt * 16 + mr) * H2_STRIDE + ks * 32 + q * 8];
#pragma unroll
            for (int mt = 0; mt < 4; ++mt)
                acc3[mt] = __builtin_amdgcn_mfma_f32_16x16x32_bf16(af[mt], g3f[ks], acc3[mt], 0, 0, 0);
        }
        // preload ALL GEMM4 B-frags (hidden under GEMM3 epilogue + b5)
        const short* A2b = A2p + wv * 4 * 512 + lane * 8;
        bf16x8 g4f[4];
#pragma unroll
        for (int ks = 0; ks < 4; ++ks) g4f[ks] = *(const bf16x8*)&A2b[ks * 512];

        {
            const int col = wv * 16 + mr;
#pragma unroll
            for (int mt = 0; mt < 4; ++mt)
#pragma unroll
                for (int r = 0; r < 4; r += 2) {
                    unsigned pk2 = f2bf2(fmaxf(acc3[mt][r], 0.f),
                                         fmaxf(acc3[mt][r + 1], 0.f));
                    xa[(mt * 16 + q * 4 + r)     * A_STRIDE + col] = (short)pk2;
                    xa[(mt * 16 + q * 4 + r + 1) * A_STRIDE + col] = (short)(pk2 >> 16);
                }
        }
        __syncthreads();   // b5: a1 ready

        // ---------- GEMM4 + in-register logits ----------
        f32x4 acc4[4];
        {
            const float bv = ab2[wv * 16 + mr];
#pragma unroll
            for (int mt = 0; mt < 4; ++mt) {
                acc4[mt][0] = bv; acc4[mt][1] = bv; acc4[mt][2] = bv; acc4[mt][3] = bv;
            }
        }
#pragma unroll
        for (int ks = 0; ks < 4; ++ks) {
            bf16x8 af[4];
#pragma unroll
            for (int mt = 0; mt < 4; ++mt)
                af[mt] = *(const bf16x8*)&xa[(mt * 16 + mr) * A_STRIDE + ks * 32 + q * 8];
#pragma unroll
            for (int mt = 0; mt < 4; ++mt)
                acc4[mt] = __builtin_amdgcn_mfma_f32_16x16x32_bf16(af[mt], g4f[ks], acc4[mt], 0, 0, 0);
        }
        const float av = A3[wv * 16 + mr];
        float pl[4][4];
#pragma unroll
        for (int mt = 0; mt < 4; ++mt)
#pragma unroll
            for (int r = 0; r < 4; ++r)
                pl[mt][r] = fmaxf(acc4[mt][r], 0.f) * av;
#pragma unroll
        for (int off = 1; off < 16; off <<= 1)
#pragma unroll
            for (int mt = 0; mt < 4; ++mt)
#pragma unroll
                for (int r = 0; r < 4; ++r)
                    pl[mt][r] += __shfl_xor(pl[mt][r], off, 64);
        if (mr == 0) {
#pragma unroll
            for (int mt = 0; mt < 4; ++mt)
#pragma unroll
                for (int r = 0; r < 4; ++r)
                    partials[wv * KK + mt * 16 + q * 4 + r] = pl[mt][r];
        }
    }
    __syncthreads();   // b6 (final barrier)

    // ---------- distributed tail: every wave computes softmax redundantly ----------
    {
        // lane k holds logit k (64 lanes = 64 paths)
        float l = ab3[0];
#pragma unroll
        for (int w = 0; w < 8; ++w) l += partials[w * KK + lane];
        float m = l;
#pragma unroll
        for (int off = 32; off > 0; off >>= 1) m = fmaxf(m, __shfl_xor(m, off, 64));
        float e = expf(l - m);
        float s = e;
#pragma unroll
        for (int off = 32; off > 0; off >>= 1) s += __shfl_xor(s, off, 64);
        wts8[wv * 64 + lane] = e / s;          // wave-local write; same-wave read below
        // out[n][col] = sum_k w[k] * h2[k][col]; wave wv covers cols wv*16..+15,
        // lane (mr,q) sums k in [q*16, q*16+16), then 2 xors combine the quads.
        const int col = wv * 16 + mr;
        const float* wl = &wts8[wv * 64 + q * 16];
        const short* hp = &xb[(q * 16) * H2_STRIDE + col];
        float acc = 0.f;
#pragma unroll
        for (int j = 0; j < 16; ++j)
            acc = fmaf(wl[j], bf2f(hp[j * H2_STRIDE]), acc);
        acc += __shfl_xor(acc, 16, 64);
        acc += __shfl_xor(acc, 32, 64);
        if (q == 0) out[(size_t)n * DD + col] = acc;
    }
}

extern "C" void kernel_launch(void* const* d_in, const int* in_sizes, int n_in,
                              void* d_out, int out_size, void* d_ws, size_t ws_size,
                              hipStream_t stream)
{
    const int*   nodes     = (const int*)d_in[0];
    const int*   paths_rel = (const int*)d_in[1];
    const int*   paths_nbr = (const int*)d_in[2];
    const int*   attrs     = (const int*)d_in[3];
    const float* u2e  = (const float*)d_in[4];
    const float* r2e  = (const float*)d_in[5];
    const float* ua2e = (const float*)d_in[6];
    const float* W1   = (const float*)d_in[7];
    const float* b1   = (const float*)d_in[8];
    const float* W2   = (const float*)d_in[9];
    const float* b2   = (const float*)d_in[10];
    const float* A1   = (const float*)d_in[11];
    const float* ab1  = (const float*)d_in[12];
    const float* A2   = (const float*)d_in[13];
    const float* ab2  = (const float*)d_in[14];
    const float* A3   = (const float*)d_in[15];
    const float* ab3  = (const float*)d_in[16];
    float* out = (float*)d_out;

    // ws: shorts W1p 131072 | W2p 32768 | A1p 16384 | A2p 16384 (=384 KB), then s1g fp32 (2 MB)
    short* wsp = (short*)d_ws;
    short* W1p = wsp;
    short* W2p = wsp + 131072;
    short* A1p = wsp + 163840;
    short* A2p = wsp + 180224;
    float* s1g = (float*)((char*)d_ws + 393216);

    hipLaunchKernelGGL(prep_all, dim3(768 + 512), dim3(256), 0, stream,
                       W1, W2, A1, A2, nodes, u2e, ab1,
                       W1p, W2p, A1p, A2p, s1g);
    hipLaunchKernelGGL(l2agg_mfma, dim3(NN), dim3(512), 0, stream,
                       paths_rel, paths_nbr, attrs, u2e, r2e, ua2e,
                       b1, b2, ab2, A3, ab3,
                       W1p, W2p, A1p, A2p, s1g, out);
}

// Round 10
// 292.360 us; speedup vs baseline: 1.0630x; 1.0630x over previous
//
#include <hip/hip_runtime.h>
#include <hip/hip_bf16.h>

#define NN 4096
#define KK 64
#define AA 8
#define DD 128

#define XH_STRIDE 264   // shorts: 256 + 8 pad (rows 16B-aligned)
#define A_STRIDE  136
#define H2_STRIDE 136
#define XREG_SZ   16896 // 64 * 264 shorts = 33792 B

typedef __bf16 bf16x8 __attribute__((ext_vector_type(8)));
typedef __bf16 bf16x2 __attribute__((ext_vector_type(2)));
typedef float  f32x4  __attribute__((ext_vector_type(4)));

__device__ __forceinline__ short f2bf(float f) {
    unsigned u = __builtin_bit_cast(unsigned, f);
    u += 0x7FFFu + ((u >> 16) & 1u);   // RNE
    return (short)(u >> 16);
}
__device__ __forceinline__ float bf2f(short s) {
    unsigned u = ((unsigned)(unsigned short)s) << 16;
    return __builtin_bit_cast(float, u);
}
__device__ __forceinline__ unsigned f2bf2(float a, float b) {
#if __has_builtin(__builtin_amdgcn_cvt_pk_bf16_f32)
    bf16x2 r = __builtin_amdgcn_cvt_pk_bf16_f32(a, b);
    return __builtin_bit_cast(unsigned, r);
#else
    return ((unsigned)(unsigned short)f2bf(a)) | (((unsigned)(unsigned short)f2bf(b)) << 16);
#endif
}
__device__ __forceinline__ void store_bf8(short* dst, float4 a, float4 b) {
    uint4 v;
    v.x = f2bf2(a.x, a.y); v.y = f2bf2(a.z, a.w);
    v.z = f2bf2(b.x, b.y); v.w = f2bf2(b.z, b.w);
    *(uint4*)dst = v;
}

// Merged prep: blocks [0,768) pack weights; blocks [768,768+512) compute s1, 8 nodes/block.
__global__ void prep_all(const float* __restrict__ W1, const float* __restrict__ W2,
                         const float* __restrict__ A1, const float* __restrict__ A2,
                         const int* __restrict__ nodes, const float* __restrict__ u2e,
                         const float* __restrict__ ab1,
                         short* __restrict__ W1p, short* __restrict__ W2p,
                         short* __restrict__ A1p, short* __restrict__ A2p,
                         float* __restrict__ s1g)
{
    if (blockIdx.x < 768) {
        int t = blockIdx.x * 256 + threadIdx.x;
        const float* src; short* dst; int Ncols, ksl, idx;
        if (t < 131072)      { src = W1; dst = W1p; Ncols = 256; ksl = 4; idx = t; }
        else if (t < 163840) { src = W2; dst = W2p; Ncols = 128; ksl = 3; idx = t - 131072; }
        else if (t < 180224) { src = A1; dst = A1p; Ncols = 128; ksl = 2; idx = t - 163840; }
        else                 { src = A2; dst = A2p; Ncols = 128; ksl = 2; idx = t - 180224; }
        int j     = idx & 7;
        int lane  = (idx >> 3) & 63;
        int fi    = idx >> 9;
        int kstep = fi & ((1 << ksl) - 1);
        int ntile = fi >> ksl;
        int k  = kstep * 32 + (lane >> 4) * 8 + j;
        int nn = ntile * 16 + (lane & 15);
        dst[idx] = f2bf(src[(size_t)k * Ncols + nn]);
    } else {
        // s1[n] = ab1 + u2e[nodes[n]] @ A1[128:256,:], 8 nodes/block
        __shared__ float rows[8][DD];
        const int b = blockIdx.x - 768;
        {
            const int r  = threadIdx.x >> 5;
            const int c4 = (threadIdx.x & 31) * 4;
            const int node = nodes[b * 8 + r];
            *(float4*)&rows[r][c4] = *(const float4*)&u2e[(size_t)node * DD + c4];
        }
        __syncthreads();
        const int h = threadIdx.x >> 7;
        const int c = threadIdx.x & 127;
        const float ab = ab1[c];
        float acc[4] = {ab, ab, ab, ab};
        for (int i = 0; i < DD; ++i) {
            const float av = A1[(size_t)(DD + i) * DD + c];
#pragma unroll
            for (int j = 0; j < 4; ++j)
                acc[j] = fmaf(rows[h * 4 + j][i], av, acc[j]);
        }
#pragma unroll
        for (int j = 0; j < 4; ++j)
            s1g[(size_t)(b * 8 + h * 4 + j) * DD + c] = acc[j];
    }
}

// Register discipline (hard-won, R6/R8/R9):
//  - launch_bounds MUST stay (512,4): (512,6) caps regs ~85/wave -> acc spill (+280 MB
//    scratch traffic, R6). Budget = 128 unified regs/wave; baseline ~64V + ~48A.
//  - NEVER let gather loads overlap GEMM1 MFMA: manual interleave (R8) and
//    compiler hoisting with no fence (R9) both spill (43/59 MB WRITE_SIZE).
//    sched_barrier(0) fences the scheduler at zero runtime cost.
__launch_bounds__(512, 4)
__global__ void l2agg_mfma(
    const int* __restrict__ paths_rel,
    const int* __restrict__ paths_nbr,
    const int* __restrict__ attrs,
    const float* __restrict__ u2e,
    const float* __restrict__ r2e,
    const float* __restrict__ ua2e,
    const float* __restrict__ b1,
    const float* __restrict__ b2,
    const float* __restrict__ ab2,
    const float* __restrict__ A3,
    const float* __restrict__ ab3,
    const short* __restrict__ W1p,
    const short* __restrict__ W2p,
    const short* __restrict__ A1p,
    const short* __restrict__ A2p,
    const float* __restrict__ s1g,
    float* __restrict__ out)
{
    // xa: xA (stride 264) -> h1 (stride 264) -> a1 (stride 136)
    // xb: xB (stride 264) -> h2 (stride 136, persists to final reduce)
    __shared__ short xa[XREG_SZ];            // 33792 B
    __shared__ short xb[XREG_SZ];            // 33792 B
    __shared__ int   idx_u[576];             // attrs(512)+nbr(64) (dead after xB) -> partials
    __shared__ float wts8[512];              // per-wave softmax weights (wave-local)
    float* partials = (float*)idx_u;         // 512 floats, born after b5

    const int n    = blockIdx.x;
    const int tid  = threadIdx.x;
    const int lane = tid & 63;
    const int wv   = tid >> 6;    // 0..7
    const int mr   = lane & 15;
    const int q    = lane >> 4;

    // ---------- async DMA prefetch: attrs + nbr indices -> LDS ----------
    {
        const int* ab = attrs + (size_t)n * KK * AA;
        __builtin_amdgcn_global_load_lds(
            (const __attribute__((address_space(1))) void*)(ab + wv * 64 + lane),
            (__attribute__((address_space(3))) void*)(idx_u + wv * 64), 4, 0, 0);
        if (wv == 0) {
            const int* nb = paths_nbr + (size_t)n * KK;
            __builtin_amdgcn_global_load_lds(
                (const __attribute__((address_space(1))) void*)(nb + lane),
                (__attribute__((address_space(3))) void*)(idx_u + 512), 4, 0, 0);
        }
    }

    // ---------- stage xA = [r1 | r2] for 64 paths ----------
#pragma unroll
    for (int pass = 0; pass < 2; ++pass) {
        const int p  = pass * 32 + (tid >> 4);
        const int t  = tid & 15;
        const int o  = t * 8;
        const int pk = n * KK + p;
        const int i0 = paths_rel[pk * 2 + 0];
        const int i1 = paths_rel[pk * 2 + 1];
        float4 r1a = *(const float4*)&r2e[(size_t)i0 * DD + o];
        float4 r1b = *(const float4*)&r2e[(size_t)i0 * DD + o + 4];
        float4 r2a = *(const float4*)&r2e[(size_t)i1 * DD + o];
        float4 r2b = *(const float4*)&r2e[(size_t)i1 * DD + o + 4];
        store_bf8(&xa[p * XH_STRIDE + o], r1a, r1b);
        store_bf8(&xa[p * XH_STRIDE + 128 + o], r2a, r2b);
    }
    __syncthreads();   // b1: xa ready, idx DMA landed

    // ---------- GEMM1 half 1 (ks 0..7 on xa), 2-deep B prefetch ----------
    const short* W1b = W1p + wv * 2 * 16 * 512 + lane * 8;  // frag(nt,ks) = W1b[nt*8192 + ks*512]
    f32x4 acc1[4][2] = {};
    bf16x8 bfc[2], bfn[2];
#pragma unroll
    for (int nt = 0; nt < 2; ++nt) bfc[nt] = *(const bf16x8*)&W1b[nt * 8192];
#pragma unroll
    for (int ks = 0; ks < 8; ++ks) {
#pragma unroll
        for (int nt = 0; nt < 2; ++nt)
            bfn[nt] = *(const bf16x8*)&W1b[nt * 8192 + (ks + 1) * 512];
        bf16x8 af[4];
#pragma unroll
        for (int mt = 0; mt < 4; ++mt)
            af[mt] = *(const bf16x8*)&xa[(mt * 16 + mr) * XH_STRIDE + ks * 32 + q * 8];
#pragma unroll
        for (int nt = 0; nt < 2; ++nt)
#pragma unroll
            for (int mt = 0; mt < 4; ++mt)
                acc1[mt][nt] = __builtin_amdgcn_mfma_f32_16x16x32_bf16(af[mt], bfc[nt], acc1[mt][nt], 0, 0, 0);
#pragma unroll
        for (int nt = 0; nt < 2; ++nt) bfc[nt] = bfn[nt];   // ks=7 carries ks=8 frags across staging
    }

    // Fence: keep xB gathers OUT of GEMM1h1's register window (R9 spill lesson).
    __builtin_amdgcn_sched_barrier(0);

    // ---------- stage xB = [ne | ae] -> xb ----------
#pragma unroll
    for (int pass = 0; pass < 2; ++pass) {
        const int p  = pass * 32 + (tid >> 4);
        const int t  = tid & 15;
        const int o  = t * 8;
        const int nb = idx_u[512 + p];
        float4 nea = *(const float4*)&u2e[(size_t)nb * DD + o];
        float4 neb = *(const float4*)&u2e[(size_t)nb * DD + o + 4];
        float4 aea = make_float4(0.f, 0.f, 0.f, 0.f);
        float4 aeb = make_float4(0.f, 0.f, 0.f, 0.f);
#pragma unroll
        for (int a = 0; a < AA; ++a) {
            const int ai = idx_u[p * AA + a];
            float4 va = *(const float4*)&ua2e[(size_t)ai * DD + o];
            float4 vb = *(const float4*)&ua2e[(size_t)ai * DD + o + 4];
            aea.x += va.x; aea.y += va.y; aea.z += va.z; aea.w += va.w;
            aeb.x += vb.x; aeb.y += vb.y; aeb.z += vb.z; aeb.w += vb.w;
        }
        store_bf8(&xb[p * XH_STRIDE + o], nea, neb);
        store_bf8(&xb[p * XH_STRIDE + 128 + o], aea, aeb);
    }
    __builtin_amdgcn_sched_barrier(0);
    __syncthreads();   // b2: xb ready; xa GEMM1h1 reads done -> xa writable later

    // ---------- GEMM1 half 2 (ks 8..15 on xb) ----------
#pragma unroll
    for (int ks = 8; ks < 16; ++ks) {
        if (ks < 15) {
#pragma unroll
            for (int nt = 0; nt < 2; ++nt)
                bfn[nt] = *(const bf16x8*)&W1b[nt * 8192 + (ks + 1) * 512];
        }
        bf16x8 af[4];
#pragma unroll
        for (int mt = 0; mt < 4; ++mt)
            af[mt] = *(const bf16x8*)&xb[(mt * 16 + mr) * XH_STRIDE + (ks - 8) * 32 + q * 8];
#pragma unroll
        for (int nt = 0; nt < 2; ++nt)
#pragma unroll
            for (int mt = 0; mt < 4; ++mt)
                acc1[mt][nt] = __builtin_amdgcn_mfma_f32_16x16x32_bf16(af[mt], bfc[nt], acc1[mt][nt], 0, 0, 0);
        if (ks < 15) {
#pragma unroll
            for (int nt = 0; nt < 2; ++nt) bfc[nt] = bfn[nt];
        }
    }

    // preload GEMM2 ks=0 B-frag; wave -> cols wv*16..wv*16+15 (mt4 x nt1: min regs)
    const short* W2b = W2p + wv * 8 * 512 + lane * 8;       // frag(ks) = W2b[ks*512]
    bf16x8 g2c = *(const bf16x8*)&W2b[0], g2n;

    // ---------- h1 = relu(acc1 + b1) -> xa (writable since b2) ----------
#pragma unroll
    for (int nt = 0; nt < 2; ++nt) {
        const int col = (wv * 2 + nt) * 16 + mr;
        const float bb = b1[col];
#pragma unroll
        for (int mt = 0; mt < 4; ++mt)
#pragma unroll
            for (int r = 0; r < 4; r += 2) {
                unsigned pk2 = f2bf2(fmaxf(acc1[mt][nt][r] + bb, 0.f),
                                     fmaxf(acc1[mt][nt][r + 1] + bb, 0.f));
                xa[(mt * 16 + q * 4 + r)     * XH_STRIDE + col] = (short)pk2;
                xa[(mt * 16 + q * 4 + r + 1) * XH_STRIDE + col] = (short)(pk2 >> 16);
            }
    }
    __syncthreads();   // b3: h1 ready; xb GEMM1h2 reads done

    // ---------- GEMM2: h2 = relu(h1 @ W2 + b2), 2-deep B prefetch ----------
    f32x4 acc2[4] = {};
#pragma unroll
    for (int ks = 0; ks < 8; ++ks) {
        if (ks < 7) g2n = *(const bf16x8*)&W2b[(ks + 1) * 512];
        bf16x8 af[4];
#pragma unroll
        for (int mt = 0; mt < 4; ++mt)
            af[mt] = *(const bf16x8*)&xa[(mt * 16 + mr) * XH_STRIDE + ks * 32 + q * 8];
#pragma unroll
        for (int mt = 0; mt < 4; ++mt)
            acc2[mt] = __builtin_amdgcn_mfma_f32_16x16x32_bf16(af[mt], g2c, acc2[mt], 0, 0, 0);
        if (ks < 7) g2c = g2n;
    }

    // preload ALL GEMM3 B-frags + s1 (hidden under GEMM2 epilogue + b4)
    const short* A1b = A1p + wv * 4 * 512 + lane * 8;
    bf16x8 g3f[4];
#pragma unroll
    for (int ks = 0; ks < 4; ++ks) g3f[ks] = *(const bf16x8*)&A1b[ks * 512];
    const float s1v = s1g[(size_t)n * DD + wv * 16 + mr];

    // GEMM2 epilogue -> h2 into xb (stride 136; xb dead since b3)
    {
        const int col = wv * 16 + mr;
        const float bb = b2[col];
#pragma unroll
        for (int mt = 0; mt < 4; ++mt)
#pragma unroll
            for (int r = 0; r < 4; r += 2) {
                unsigned pk2 = f2bf2(fmaxf(acc2[mt][r] + bb, 0.f),
                                     fmaxf(acc2[mt][r + 1] + bb, 0.f));
                xb[(mt * 16 + q * 4 + r)     * H2_STRIDE + col] = (short)pk2;
                xb[(mt * 16 + q * 4 + r + 1) * H2_STRIDE + col] = (short)(pk2 >> 16);
            }
    }
    __syncthreads();   // b4: h2 ready; xa GEMM2 reads done

    // ---------- GEMM3: a1 = relu(h2 @ A1[:128] + s1) -> xa (stride 136) ----------
    {
        f32x4 acc3[4];
#pragma unroll
        for (int mt = 0; mt < 4; ++mt) {
            acc3[mt][0] = s1v; acc3[mt][1] = s1v; acc3[mt][2] = s1v; acc3[mt][3] = s1v;
        }
#pragma unroll
        for (int ks = 0; ks < 4; ++ks) {
            bf16x8 af[4];
#pragma unroll
            for (int mt = 0; mt < 4; ++mt)
                af[mt] = *(const bf16x8*)&xb[(mt * 16 + mr) * H2_STRIDE + ks * 32 + q * 8];
#pragma unroll
            for (int mt = 0; mt < 4; ++mt)
                acc3[mt] = __builtin_amdgcn_mfma_f32_16x16x32_bf16(af[mt], g3f[ks], acc3[mt], 0, 0, 0);
        }
        // preload ALL GEMM4 B-frags (hidden under GEMM3 epilogue + b5)
        const short* A2b = A2p + wv * 4 * 512 + lane * 8;
        bf16x8 g4f[4];
#pragma unroll
        for (int ks = 0; ks < 4; ++ks) g4f[ks] = *(const bf16x8*)&A2b[ks * 512];

        {
            const int col = wv * 16 + mr;
#pragma unroll
            for (int mt = 0; mt < 4; ++mt)
#pragma unroll
                for (int r = 0; r < 4; r += 2) {
                    unsigned pk2 = f2bf2(fmaxf(acc3[mt][r], 0.f),
                                         fmaxf(acc3[mt][r + 1], 0.f));
                    xa[(mt * 16 + q * 4 + r)     * A_STRIDE + col] = (short)pk2;
                    xa[(mt * 16 + q * 4 + r + 1) * A_STRIDE + col] = (short)(pk2 >> 16);
                }
        }
        __syncthreads();   // b5: a1 ready

        // ---------- GEMM4 + in-register logits ----------
        f32x4 acc4[4];
        {
            const float bv = ab2[wv * 16 + mr];
#pragma unroll
            for (int mt = 0; mt < 4; ++mt) {
                acc4[mt][0] = bv; acc4[mt][1] = bv; acc4[mt][2] = bv; acc4[mt][3] = bv;
            }
        }
#pragma unroll
        for (int ks = 0; ks < 4; ++ks) {
            bf16x8 af[4];
#pragma unroll
            for (int mt = 0; mt < 4; ++mt)
                af[mt] = *(const bf16x8*)&xa[(mt * 16 + mr) * A_STRIDE + ks * 32 + q * 8];
#pragma unroll
            for (int mt = 0; mt < 4; ++mt)
                acc4[mt] = __builtin_amdgcn_mfma_f32_16x16x32_bf16(af[mt], g4f[ks], acc4[mt], 0, 0, 0);
        }
        const float av = A3[wv * 16 + mr];
        float pl[4][4];
#pragma unroll
        for (int mt = 0; mt < 4; ++mt)
#pragma unroll
            for (int r = 0; r < 4; ++r)
                pl[mt][r] = fmaxf(acc4[mt][r], 0.f) * av;
#pragma unroll
        for (int off = 1; off < 16; off <<= 1)
#pragma unroll
            for (int mt = 0; mt < 4; ++mt)
#pragma unroll
                for (int r = 0; r < 4; ++r)
                    pl[mt][r] += __shfl_xor(pl[mt][r], off, 64);
        if (mr == 0) {
#pragma unroll
            for (int mt = 0; mt < 4; ++mt)
#pragma unroll
                for (int r = 0; r < 4; ++r)
                    partials[wv * KK + mt * 16 + q * 4 + r] = pl[mt][r];
        }
    }
    __syncthreads();   // b6 (final barrier)

    // ---------- distributed tail: every wave computes softmax redundantly ----------
    {
        float l = ab3[0];
#pragma unroll
        for (int w = 0; w < 8; ++w) l += partials[w * KK + lane];
        float m = l;
#pragma unroll
        for (int off = 32; off > 0; off >>= 1) m = fmaxf(m, __shfl_xor(m, off, 64));
        float e = expf(l - m);
        float s = e;
#pragma unroll
        for (int off = 32; off > 0; off >>= 1) s += __shfl_xor(s, off, 64);
        wts8[wv * 64 + lane] = e / s;          // wave-local write; same-wave read below
        // out[n][col]: wave wv covers cols wv*16..+15; lane (mr,q) sums k in [q*16,q*16+16)
        const int col = wv * 16 + mr;
        const float* wl = &wts8[wv * 64 + q * 16];
        const short* hp = &xb[(q * 16) * H2_STRIDE + col];
        float acc = 0.f;
#pragma unroll
        for (int j = 0; j < 16; ++j)
            acc = fmaf(wl[j], bf2f(hp[j * H2_STRIDE]), acc);
        acc += __shfl_xor(acc, 16, 64);
        acc += __shfl_xor(acc, 32, 64);
        if (q == 0) out[(size_t)n * DD + col] = acc;
    }
}

extern "C" void kernel_launch(void* const* d_in, const int* in_sizes, int n_in,
                              void* d_out, int out_size, void* d_ws, size_t ws_size,
                              hipStream_t stream)
{
    const int*   nodes     = (const int*)d_in[0];
    const int*   paths_rel = (const int*)d_in[1];
    const int*   paths_nbr = (const int*)d_in[2];
    const int*   attrs     = (const int*)d_in[3];
    const float* u2e  = (const float*)d_in[4];
    const float* r2e  = (const float*)d_in[5];
    const float* ua2e = (const float*)d_in[6];
    const float* W1   = (const float*)d_in[7];
    const float* b1   = (const float*)d_in[8];
    const float* W2   = (const float*)d_in[9];
    const float* b2   = (const float*)d_in[10];
    const float* A1   = (const float*)d_in[11];
    const float* ab1  = (const float*)d_in[12];
    const float* A2   = (const float*)d_in[13];
    const float* ab2  = (const float*)d_in[14];
    const float* A3   = (const float*)d_in[15];
    const float* ab3  = (const float*)d_in[16];
    float* out = (float*)d_out;

    // ws: shorts W1p 131072 | W2p 32768 | A1p 16384 | A2p 16384 (=384 KB), then s1g fp32 (2 MB)
    short* wsp = (short*)d_ws;
    short* W1p = wsp;
    short* W2p = wsp + 131072;
    short* A1p = wsp + 163840;
    short* A2p = wsp + 180224;
    float* s1g = (float*)((char*)d_ws + 393216);

    hipLaunchKernelGGL(prep_all, dim3(768 + 512), dim3(256), 0, stream,
                       W1, W2, A1, A2, nodes, u2e, ab1,
                       W1p, W2p, A1p, A2p, s1g);
    hipLaunchKernelGGL(l2agg_mfma, dim3(NN), dim3(512), 0, stream,
                       paths_rel, paths_nbr, attrs, u2e, r2e, ua2e,
                       b1, b2, ab2, A3, ab3,
                       W1p, W2p, A1p, A2p, s1g, out);
}